// Round 2
// baseline (451.001 us; speedup 1.0000x reference)
//
#include <hip/hip_runtime.h>

typedef unsigned short u16;
typedef float f4 __attribute__((ext_vector_type(4)));

// ---------- bf16 helpers ----------
static __device__ __forceinline__ float bf2f(u16 u) {
    union { unsigned int i; float f; } v;
    v.i = ((unsigned int)u) << 16;
    return v.f;
}
static __device__ __forceinline__ u16 f2bf(float f) {
    union { float f; unsigned int i; } v;
    v.f = f;
    unsigned int x = v.i;
    x += 0x7fffu + ((x >> 16) & 1u);   // RNE
    return (u16)(x >> 16);
}
// dtype-flexible load: dt==0 -> bf16, dt==1 -> f32
static __device__ __forceinline__ float gld(int dt, const void* p, int i) {
    return dt ? ((const float*)p)[i] : bf2f(((const u16*)p)[i]);
}

// ---------- ws layout (bytes) ----------
#define FLAG_OFF      0u
#define WF_OFF        64u          // 8545 floats = 34180 B
#define GRID_OFF      34304u
#define PLANES_F_OFF  GRID_OFF                     // 1572864 floats
#define VOL_F_OFF     (GRID_OFF + 6291456u)        // 2097152 floats
#define LINES_F_OFF   (GRID_OFF + 6291456u + 8388608u)  // 12288 floats
#define NEED_FAST     (GRID_OFF + 6291456u + 8388608u + 49152u)  // 14763520

// fp32 weight region (floats): Wf[3072] | bv[96] | W1t[5120] | b1v[128] | W2v[128] | b2v[1]

// =====================================================================
// dtype detect: count bf16-plausible exponents in first 64 u16s of coords
// =====================================================================
__global__ void kp_detect(const u16* __restrict__ cu, int* __restrict__ flag) {
    int t = threadIdx.x;            // 64 threads = 1 wave
    u16 v = cu[t];
    int e = (v >> 7) & 0xFF;
    bool inr = (e >= 90) && (e <= 126);
    unsigned long long m = __ballot(inr);
    if (t == 0) *flag = (__popcll(m) >= 56) ? 0 : 1;   // 0=bf16, 1=f32
}

// =====================================================================
// weights -> fp32 (W1 transposed to [128][40])
// =====================================================================
__global__ void kp_prep_weights(const void* __restrict__ Wx, const void* __restrict__ bx,
                                const void* __restrict__ Wy, const void* __restrict__ by,
                                const void* __restrict__ Wz, const void* __restrict__ bz,
                                const void* __restrict__ W1, const void* __restrict__ b1,
                                const void* __restrict__ W2, const void* __restrict__ b2,
                                float* __restrict__ wbase, const int* __restrict__ flag)
{
    int dt = *flag;
    float* Wf  = wbase;            // 3*1024
    float* bv  = Wf + 3072;        // 96
    float* W1t = bv + 96;          // 5120
    float* b1v = W1t + 5120;       // 128
    float* W2v = b1v + 128;        // 128
    float* b2v = W2v + 128;        // 1
    int t = blockIdx.x * blockDim.x + threadIdx.x;
    if (t < 3072) {
        int m = t >> 10, r = t & 1023;
        const void* s = (m == 0) ? Wx : (m == 1) ? Wy : Wz;
        Wf[t] = gld(dt, s, r);
    } else if (t < 3168) {
        int r = t - 3072;
        int m = r >> 5, c = r & 31;
        const void* s = (m == 0) ? bx : (m == 1) ? by : bz;
        bv[r] = gld(dt, s, c);
    } else if (t < 8288) {
        int r = t - 3168;                      // r = j*40+i
        int j = r / 40, i = r - j * 40;
        W1t[r] = gld(dt, W1, i * 128 + j);
    } else if (t < 8416) {
        b1v[t - 8288] = gld(dt, b1, t - 8288);
    } else if (t < 8544) {
        W2v[t - 8416] = gld(dt, W2, t - 8416);
    } else if (t == 8544) {
        b2v[0] = gld(dt, b2, 0);
    }
}

// =====================================================================
// grids -> fp32 channel-last (fast tier only)
// =====================================================================
__global__ void kp_prep_grids(const void* __restrict__ lx, const void* __restrict__ ly,
                              const void* __restrict__ lz,
                              const void* __restrict__ pxy, const void* __restrict__ pyz,
                              const void* __restrict__ pxz,
                              const void* __restrict__ vol,
                              float* __restrict__ planes_f, float* __restrict__ vol_f,
                              float* __restrict__ lines_f, const int* __restrict__ flag)
{
    int dt = *flag;
    const int NPLANE = 3 * 524288;
    const int NVOL   = 2097152;
    int t = blockIdx.x * blockDim.x + threadIdx.x;   // 14384*256 = 3682304 exactly
    if (t < NPLANE) {
        int pl = t >> 19;
        int r  = t & 524287;
        int c = r & 31, pos = r >> 5;
        const void* src = (pl == 0) ? pxy : (pl == 1) ? pyz : pxz;
        planes_f[t] = gld(dt, src, c * 16384 + pos);
    } else if (t < NPLANE + NVOL) {
        int r = t - NPLANE;
        int c = r & 7, pos = r >> 3;
        vol_f[r] = gld(dt, vol, c * 262144 + pos);
    } else {
        int r = t - NPLANE - NVOL;
        int l = r >> 12, rr = r & 4095;
        int c = rr & 31, n = rr >> 5;
        const void* src = (l == 0) ? lx : (l == 1) ? ly : lz;
        lines_f[r] = gld(dt, src, c * 128 + n);
    }
}

// =====================================================================
// shared math
// =====================================================================
struct Samp { int i0, i1; float w0, w1; };

static __device__ __forceinline__ Samp make_samp(float g, int N) {
    float ix = (g + 1.0f) * 0.5f * (float)(N - 1);
    float fl = floorf(ix);
    float w  = ix - fl;
    int i  = (int)fl;
    int i1 = i + 1;
    float v0 = (i  >= 0 && i  < N) ? 1.0f : 0.0f;
    float v1 = (i1 >= 0 && i1 < N) ? 1.0f : 0.0f;
    Samp s;
    s.w0 = (1.0f - w) * v0;
    s.w1 = w * v1;
    s.i0 = min(max(i, 0), N - 1);
    s.i1 = min(max(i1, 0), N - 1);
    return s;
}

// fused term (fast tier): feat[o] += phi_line[o] * phi_plane[o], shared W/b
static __device__ __forceinline__ void term_fused(
    const float* __restrict__ Lf, const Samp& sl,
    const float* __restrict__ Pf, const Samp& sa, const Samp& sb,
    const float* __restrict__ W, const float* __restrict__ b,
    float (&feat)[40])
{
    float ta[32], tb[32];
#pragma unroll
    for (int o = 0; o < 32; ++o) { ta[o] = b[o]; tb[o] = b[o]; }
    const f4* l0  = (const f4*)(Lf + sl.i0 * 32);
    const f4* l1  = (const f4*)(Lf + sl.i1 * 32);
    const f4* p00 = (const f4*)(Pf + (sb.i0 * 128 + sa.i0) * 32);
    const f4* p01 = (const f4*)(Pf + (sb.i0 * 128 + sa.i1) * 32);
    const f4* p10 = (const f4*)(Pf + (sb.i1 * 128 + sa.i0) * 32);
    const f4* p11 = (const f4*)(Pf + (sb.i1 * 128 + sa.i1) * 32);
    float w00 = sb.w0 * sa.w0, w01 = sb.w0 * sa.w1;
    float w10 = sb.w1 * sa.w0, w11 = sb.w1 * sa.w1;
#pragma unroll 1
    for (int cc = 0; cc < 8; ++cc) {
        f4 a0 = l0[cc], a1 = l1[cc];
        f4 q00 = p00[cc], q01 = p01[cc], q10 = p10[cc], q11 = p11[cc];
        const float* wr = W + cc * 128;
#pragma unroll
        for (int k = 0; k < 4; ++k) {
            float el = sl.w0 * a0[k] + sl.w1 * a1[k];
            float ep = w00 * q00[k] + w01 * q01[k] + w10 * q10[k] + w11 * q11[k];
            float r1 = fmaxf(el, 0.0f);
            float r2 = fmaxf(ep, 0.0f);
#pragma unroll
            for (int o = 0; o < 32; ++o) {
                float w = wr[k * 32 + o];
                ta[o] = fmaf(r1, w, ta[o]);
                tb[o] = fmaf(r2, w, tb[o]);
            }
        }
    }
#pragma unroll
    for (int o = 0; o < 32; ++o) feat[o] = fmaf(ta[o], tb[o], feat[o]);
}

// head: common to both mains
static __device__ __forceinline__ float head_mlp(
    const float (&feat)[40], const float* __restrict__ W1t,
    const float* __restrict__ b1v, const float* __restrict__ W2v,
    const float* __restrict__ b2v)
{
    float acc_out = b2v[0];
#pragma unroll 2
    for (int j = 0; j < 128; ++j) {
        float acc = b1v[j];
        const float* wr = W1t + j * 40;
#pragma unroll
        for (int i = 0; i < 40; ++i)
            acc = fmaf(feat[i], wr[i], acc);
        acc_out = fmaf(fmaxf(acc, 0.0f), W2v[j], acc_out);
    }
    return acc_out;
}

// =====================================================================
// fast main: fp32 channel-last grids in ws
// =====================================================================
__global__ __launch_bounds__(256) void kp_main_fast(
    const void* __restrict__ coords,
    const float* __restrict__ planes_f, const float* __restrict__ vol_f,
    const float* __restrict__ lines_f,
    const float* __restrict__ wbase, const int* __restrict__ flag,
    void* __restrict__ out, int M)
{
    int dt = *flag;
    const float* Wf  = wbase;
    const float* bv  = Wf + 3072;
    const float* W1t = bv + 96;
    const float* b1v = W1t + 5120;
    const float* W2v = b1v + 128;
    const float* b2v = W2v + 128;

    int p = blockIdx.x * 256 + threadIdx.x;
    p = min(p, M - 1);

    float x = gld(dt, coords, p * 3 + 0);
    float y = gld(dt, coords, p * 3 + 1);
    float z = gld(dt, coords, p * 3 + 2);

    Samp sx = make_samp(x, 128), sy = make_samp(y, 128), sz = make_samp(z, 128);

    float feat[40];
#pragma unroll
    for (int o = 0; o < 32; ++o) feat[o] = 0.0f;

    // A: line_x & plane_yz(gx=y,gy=z) with Wx
    term_fused(lines_f + 0 * 4096, sx, planes_f + 1 * 524288, sy, sz, Wf + 0,    bv + 0,  feat);
    // B: line_y & plane_xz(gx=x,gy=z) with Wy
    term_fused(lines_f + 1 * 4096, sy, planes_f + 2 * 524288, sx, sz, Wf + 1024, bv + 32, feat);
    // C: line_z & plane_xy(gx=x,gy=y) with Wz
    term_fused(lines_f + 2 * 4096, sz, planes_f + 0 * 524288, sx, sy, Wf + 2048, bv + 64, feat);

    // volume
    Samp vx = make_samp(x, 64), vy = make_samp(y, 64), vz = make_samp(z, 64);
#pragma unroll
    for (int c = 0; c < 8; ++c) feat[32 + c] = 0.0f;
#pragma unroll
    for (int corner = 0; corner < 8; ++corner) {
        int dx = corner & 1, dy = (corner >> 1) & 1, dz = corner >> 2;
        int xi = dx ? vx.i1 : vx.i0;
        int yi = dy ? vy.i1 : vy.i0;
        int zi = dz ? vz.i1 : vz.i0;
        float w = (dx ? vx.w1 : vx.w0) * (dy ? vy.w1 : vy.w0) * (dz ? vz.w1 : vz.w0);
        const f4* q = (const f4*)(vol_f + (((zi * 64) + yi) * 64 + xi) * 8);
        f4 v0 = q[0], v1 = q[1];
#pragma unroll
        for (int c = 0; c < 4; ++c) {
            feat[32 + c] = fmaf(w, v0[c], feat[32 + c]);
            feat[36 + c] = fmaf(w, v1[c], feat[36 + c]);
        }
    }

    float r = head_mlp(feat, W1t, b1v, W2v, b2v);
    if (dt) ((float*)out)[p] = r;
    else    ((u16*)out)[p] = f2bf(r);
}

// =====================================================================
// direct main (fallback): channel-major gathers from original buffers
// =====================================================================
static __device__ __forceinline__ void term_direct(
    int dt, const void* __restrict__ L, const Samp& sl,
    const void* __restrict__ P, const Samp& sa, const Samp& sb,
    const float* __restrict__ W, const float* __restrict__ b,
    float (&feat)[40])
{
    float ta[32], tb[32];
#pragma unroll
    for (int o = 0; o < 32; ++o) { ta[o] = b[o]; tb[o] = b[o]; }
    float w00 = sb.w0 * sa.w0, w01 = sb.w0 * sa.w1;
    float w10 = sb.w1 * sa.w0, w11 = sb.w1 * sa.w1;
    int i00 = sb.i0 * 128 + sa.i0, i01 = sb.i0 * 128 + sa.i1;
    int i10 = sb.i1 * 128 + sa.i0, i11 = sb.i1 * 128 + sa.i1;
#pragma unroll 1
    for (int c = 0; c < 32; ++c) {
        float el = sl.w0 * gld(dt, L, c * 128 + sl.i0)
                 + sl.w1 * gld(dt, L, c * 128 + sl.i1);
        float ep = w00 * gld(dt, P, c * 16384 + i00)
                 + w01 * gld(dt, P, c * 16384 + i01)
                 + w10 * gld(dt, P, c * 16384 + i10)
                 + w11 * gld(dt, P, c * 16384 + i11);
        float r1 = fmaxf(el, 0.0f);
        float r2 = fmaxf(ep, 0.0f);
        const float* wr = W + c * 32;
#pragma unroll
        for (int o = 0; o < 32; ++o) {
            float w = wr[o];
            ta[o] = fmaf(r1, w, ta[o]);
            tb[o] = fmaf(r2, w, tb[o]);
        }
    }
#pragma unroll
    for (int o = 0; o < 32; ++o) feat[o] = fmaf(ta[o], tb[o], feat[o]);
}

__global__ __launch_bounds__(256) void kp_main_direct(
    const void* __restrict__ coords,
    const void* __restrict__ lx, const void* __restrict__ ly, const void* __restrict__ lz,
    const void* __restrict__ pxy, const void* __restrict__ pyz, const void* __restrict__ pxz,
    const void* __restrict__ vol,
    const float* __restrict__ wbase, const int* __restrict__ flag,
    void* __restrict__ out, int M)
{
    int dt = *flag;
    const float* Wf  = wbase;
    const float* bv  = Wf + 3072;
    const float* W1t = bv + 96;
    const float* b1v = W1t + 5120;
    const float* W2v = b1v + 128;
    const float* b2v = W2v + 128;

    int p = blockIdx.x * 256 + threadIdx.x;
    p = min(p, M - 1);

    float x = gld(dt, coords, p * 3 + 0);
    float y = gld(dt, coords, p * 3 + 1);
    float z = gld(dt, coords, p * 3 + 2);

    Samp sx = make_samp(x, 128), sy = make_samp(y, 128), sz = make_samp(z, 128);

    float feat[40];
#pragma unroll
    for (int o = 0; o < 32; ++o) feat[o] = 0.0f;

    term_direct(dt, lx, sx, pyz, sy, sz, Wf + 0,    bv + 0,  feat);
    term_direct(dt, ly, sy, pxz, sx, sz, Wf + 1024, bv + 32, feat);
    term_direct(dt, lz, sz, pxy, sx, sy, Wf + 2048, bv + 64, feat);

    Samp vx = make_samp(x, 64), vy = make_samp(y, 64), vz = make_samp(z, 64);
#pragma unroll
    for (int c = 0; c < 8; ++c) feat[32 + c] = 0.0f;
#pragma unroll 1
    for (int corner = 0; corner < 8; ++corner) {
        int dx = corner & 1, dy = (corner >> 1) & 1, dz = corner >> 2;
        int xi = dx ? vx.i1 : vx.i0;
        int yi = dy ? vy.i1 : vy.i0;
        int zi = dz ? vz.i1 : vz.i0;
        float w = (dx ? vx.w1 : vx.w0) * (dy ? vy.w1 : vy.w0) * (dz ? vz.w1 : vz.w0);
        int pos = ((zi * 64) + yi) * 64 + xi;
#pragma unroll
        for (int c = 0; c < 8; ++c)
            feat[32 + c] = fmaf(w, gld(dt, vol, c * 262144 + pos), feat[32 + c]);
    }

    float r = head_mlp(feat, W1t, b1v, W2v, b2v);
    if (dt) ((float*)out)[p] = r;
    else    ((u16*)out)[p] = f2bf(r);
}

// =====================================================================
extern "C" void kernel_launch(void* const* d_in, const int* in_sizes, int n_in,
                              void* d_out, int out_size, void* d_ws, size_t ws_size,
                              hipStream_t stream) {
    const void* coords = d_in[0];
    const void* lx  = d_in[1];
    const void* ly  = d_in[2];
    const void* lz  = d_in[3];
    const void* pxy = d_in[4];
    const void* pyz = d_in[5];
    const void* pxz = d_in[6];
    const void* vol = d_in[7];
    const void* Wx  = d_in[8];
    const void* bx  = d_in[9];
    const void* Wy  = d_in[10];
    const void* by  = d_in[11];
    const void* Wz  = d_in[12];
    const void* bz  = d_in[13];
    const void* W1  = d_in[14];
    const void* b1  = d_in[15];
    const void* W2  = d_in[16];
    const void* b2  = d_in[17];

    int M = in_sizes[0] / 3;

    char* ws = (char*)d_ws;
    int*   flag     = (int*)(ws + FLAG_OFF);
    float* wbase    = (float*)(ws + WF_OFF);
    float* planes_f = (float*)(ws + PLANES_F_OFF);
    float* vol_f    = (float*)(ws + VOL_F_OFF);
    float* lines_f  = (float*)(ws + LINES_F_OFF);

    kp_detect<<<1, 64, 0, stream>>>((const u16*)coords, flag);
    kp_prep_weights<<<34, 256, 0, stream>>>(Wx, bx, Wy, by, Wz, bz, W1, b1, W2, b2,
                                            wbase, flag);

    int blocks = (M + 255) / 256;
    if (ws_size >= (size_t)NEED_FAST) {
        kp_prep_grids<<<14384, 256, 0, stream>>>(lx, ly, lz, pxy, pyz, pxz, vol,
                                                 planes_f, vol_f, lines_f, flag);
        kp_main_fast<<<blocks, 256, 0, stream>>>(coords, planes_f, vol_f, lines_f,
                                                 wbase, flag, d_out, M);
    } else {
        kp_main_direct<<<blocks, 256, 0, stream>>>(coords, lx, ly, lz, pxy, pyz, pxz,
                                                   vol, wbase, flag, d_out, M);
    }
}